// Round 3
// baseline (191.236 us; speedup 1.0000x reference)
//
#include <hip/hip_runtime.h>

typedef __attribute__((ext_vector_type(8))) short short8;
typedef __attribute__((ext_vector_type(4))) short short4v;
typedef __attribute__((ext_vector_type(4))) float floatx4;

// fp32 -> bf16 round-to-nearest-even (inputs finite)
static __device__ __forceinline__ unsigned short f2bf(float f) {
    union { float f; unsigned int u; } v; v.f = f;
    unsigned int u = v.u;
    return (unsigned short)((u + 0x7FFFu + ((u >> 16) & 1u)) >> 16);
}

// Fused convert kernel (unchanged from round 2):
//   blocks [0, nblk_nodes): node_emb fp32 -> bf16
//   blocks [nblk_nodes, +8): W1 [256,128] -> W1^T bf16 [128,256], LDS-tiled
__global__ void cvt_kernel(const float* __restrict__ x, unsigned short* __restrict__ y,
                           int n4, const float* __restrict__ w1,
                           unsigned short* __restrict__ w1t, int nblk_nodes) {
    __shared__ unsigned short sT[32 * 130];
    if ((int)blockIdx.x < nblk_nodes) {
        int i = blockIdx.x * 256 + threadIdx.x;
        if (i >= n4) return;
        const float4 v = ((const float4*)x)[i];
        ushort4 o;
        o.x = f2bf(v.x); o.y = f2bf(v.y); o.z = f2bf(v.z); o.w = f2bf(v.w);
        ((ushort4*)y)[i] = o;
    } else {
        const int b = blockIdx.x - nblk_nodes;
        const int k0 = b * 32;
        const int tid = threadIdx.x;
#pragma unroll
        for (int i = 0; i < 16; i++) {
            int idx = tid + i * 256;
            int k = idx >> 7, n = idx & 127;
            sT[k * 130 + n] = f2bf(w1[(k0 + k) * 128 + n]);
        }
        __syncthreads();
#pragma unroll
        for (int i = 0; i < 16; i++) {
            int idx = tid + i * 256;
            int n = idx >> 5, k = idx & 31;
            w1t[n * 256 + k0 + k] = sT[k * 130 + n];
        }
    }
}

// Main kernel, transposed formulation:
//   GEMM1: h^T = W1^T (A-operand, from LDS) x edge_emb^T (B-operand, gathered)
//   D1 C-layout: row = h-col (lq*4+i), col = edge (l15)  ==  B-fragment layout
//   of mfma_f32_16x16x16_bf16 for GEMM2 (contract over h-cols) -> no shuffles.
// Block 512 = 8 waves: edge-group g = wave>>1 (64 edges), col-half = wave&1.
// K-loop has NO barriers: full W1^T staged once (64KB, XOR-swizzled), gather
// double-buffered depth-2 in a register ring.
__global__ __launch_bounds__(512, 4) void edge_mlp_kernel(
    const unsigned short* __restrict__ nodes,  // [N,128] bf16 bits
    const unsigned short* __restrict__ w1t,    // [128,256] bf16 bits (W1^T)
    const int* __restrict__ eidx,              // [2,E] int32
    const float* __restrict__ b1,              // [128]
    const float* __restrict__ w2,              // [128,2]
    const float* __restrict__ b2p,             // [2]
    float* __restrict__ out,                   // [E,2]
    int E, int n_nodes)
{
    __shared__ unsigned short sW[128 * 256];   // 64KB: all of W1^T, swizzled
    __shared__ float2 sP[2][256];              // 2KB: per-col-half partials

    const int tid  = threadIdx.x;
    const int lane = tid & 63;
    const int wave = tid >> 6;      // 0..7
    const int g    = wave >> 1;     // edge group 0..3
    const int half = wave & 1;      // column half
    const int l15  = lane & 15;     // B-frag n (edge) / A-frag m (h-col)
    const int lq   = lane >> 4;     // k-quad
    const long e0  = (long)blockIdx.x * 256 + g * 64;

    // Gather byte offsets for this wave's 4 edge-tiles.
    int offs[4], offd[4];
#pragma unroll
    for (int nt = 0; nt < 4; nt++) {
        long e = e0 + nt * 16 + l15;
        if (e >= E) e = E - 1;
        int s = eidx[e];
        int d = eidx[(long)E + e];
        s = (s < 0) ? 0 : (s >= n_nodes ? n_nodes - 1 : s);
        d = (d < 0) ? 0 : (d >= n_nodes ? n_nodes - 1 : d);
        offs[nt] = s << 8;  // 256 B per node row
        offd[nt] = d << 8;
    }

    // Stage all of W1^T, 16B slot s of row n stored at s' = (s&16)|((s^n)&15).
    // Read pattern (16 rows stride 512B, 4 lq k-offsets) lands 8 lanes per
    // bank-quad -> conflict-free.
#pragma unroll
    for (int i = 0; i < 8; i++) {
        int u = tid + i * 512;         // 0..4095 16B-units
        int n = u >> 5, s = u & 31;
        int sp = (s & 16) | ((s ^ n) & 15);
        *(short8*)&sW[n * 256 + sp * 8] = *(const short8*)&w1t[n * 256 + s * 8];
    }

    const char* nbase = (const char*)nodes;
    const int lbo = lq * 16;           // lane byte offset within a 64B k-step

    // Prefetch ring depth 2 (steps 0,1 = src row), issued before the barrier.
    short8 ring[2][4];
#pragma unroll
    for (int p = 0; p < 2; p++)
#pragma unroll
        for (int nt = 0; nt < 4; nt++)
            ring[p][nt] = *(const short8*)(nbase + offs[nt] + p * 64 + lbo);

    __syncthreads();

    floatx4 acc[4][4];
#pragma unroll
    for (int mt = 0; mt < 4; mt++)
#pragma unroll
        for (int nt = 0; nt < 4; nt++) acc[mt][nt] = (floatx4){0.f, 0.f, 0.f, 0.f};

    // Barrier-free K-loop: 8 steps of K=32.
#pragma unroll
    for (int ks = 0; ks < 8; ks++) {
        const int s  = ks * 4 + lq;
        const int sp = (s & 16) | ((s ^ l15) & 15);
#pragma unroll
        for (int mt = 0; mt < 4; mt++) {
            const int n = half * 64 + mt * 16 + l15;
            const short8 af = *(const short8*)&sW[n * 256 + sp * 8];
#pragma unroll
            for (int nt = 0; nt < 4; nt++)
                acc[mt][nt] = __builtin_amdgcn_mfma_f32_16x16x32_bf16(
                    af, ring[ks & 1][nt], acc[mt][nt], 0, 0, 0);
        }
        if (ks < 6) {                    // refill slot for step ks+2
            const int ksn = ks + 2;
            const int cb = (ksn & 3) * 64 + lbo;
            const int* of = (ksn < 4) ? offs : offd;
#pragma unroll
            for (int nt = 0; nt < 4; nt++)
                ring[ks & 1][nt] = *(const short8*)(nbase + of[nt] + cb);
        }
    }

    // GEMM2 via mfma_f32_16x16x16_bf16: out^T[ch][edge] partial over this
    // wave's 64 h-cols. A2 = W2^T (lanes l15>=2 zero), B2 = relu(h+b1) packed
    // straight from acc (layout matches exactly).
    short4v a2[4];
#pragma unroll
    for (int kt = 0; kt < 4; kt++) {
        const int k2b = half * 64 + kt * 16 + lq * 4;
        const float4 fa = *(const float4*)&w2[k2b * 2];
        const float4 fb = *(const float4*)&w2[k2b * 2 + 4];
        float j0 = (l15 == 1) ? fa.y : fa.x;
        float j1 = (l15 == 1) ? fa.w : fa.z;
        float j2 = (l15 == 1) ? fb.y : fb.x;
        float j3 = (l15 == 1) ? fb.w : fb.z;
        if (l15 >= 2) { j0 = 0.f; j1 = 0.f; j2 = 0.f; j3 = 0.f; }
        short4v t;
        t[0] = (short)f2bf(j0); t[1] = (short)f2bf(j1);
        t[2] = (short)f2bf(j2); t[3] = (short)f2bf(j3);
        a2[kt] = t;
    }
    floatx4 acc2[4];
#pragma unroll
    for (int nt = 0; nt < 4; nt++) acc2[nt] = (floatx4){0.f, 0.f, 0.f, 0.f};
#pragma unroll
    for (int kt = 0; kt < 4; kt++) {
        const float4 bv = *(const float4*)&b1[half * 64 + kt * 16 + lq * 4];
#pragma unroll
        for (int nt = 0; nt < 4; nt++) {
            short4v bf;
            bf[0] = (short)f2bf(fmaxf(acc[kt][nt][0] + bv.x, 0.f));
            bf[1] = (short)f2bf(fmaxf(acc[kt][nt][1] + bv.y, 0.f));
            bf[2] = (short)f2bf(fmaxf(acc[kt][nt][2] + bv.z, 0.f));
            bf[3] = (short)f2bf(fmaxf(acc[kt][nt][3] + bv.w, 0.f));
            acc2[nt] = __builtin_amdgcn_mfma_f32_16x16x16bf16_1k(
                a2[kt], bf, acc2[nt], 0, 0, 0);
        }
    }
    // D2: col=l15=edge, row=lq*4+i=channel -> rows 0,1 live in lq==0 lanes.
    if (lq == 0) {
#pragma unroll
        for (int nt = 0; nt < 4; nt++) {
            float2 o;
            o.x = acc2[nt][0];
            o.y = acc2[nt][1];
            sP[half][g * 64 + nt * 16 + l15] = o;
        }
    }
    __syncthreads();

    // Combine halves + b2; coalesced 4B stores (512 thr = 256 edges x 2 ch).
    {
        const int el = tid >> 1, ch = tid & 1;
        const long e = (long)blockIdx.x * 256 + el;
        if (e < E) {
            const float* p0 = (const float*)&sP[0][el];
            const float* p1 = (const float*)&sP[1][el];
            out[e * 2 + ch] = p0[ch] + p1[ch] + b2p[ch];
        }
    }
}

extern "C" void kernel_launch(void* const* d_in, const int* in_sizes, int n_in,
                              void* d_out, int out_size, void* d_ws, size_t ws_size,
                              hipStream_t stream) {
    const float* node_emb = (const float*)d_in[0];
    const int*   eidx     = (const int*)d_in[1];
    const float* W1       = (const float*)d_in[2];
    const float* b1       = (const float*)d_in[3];
    const float* W2       = (const float*)d_in[4];
    const float* b2       = (const float*)d_in[5];
    float* out = (float*)d_out;

    const int n_node_elems = in_sizes[0];        // N*128
    const int n_nodes = n_node_elems / 128;
    const int E = in_sizes[1] / 2;

    unsigned short* nodes_bf16 = (unsigned short*)d_ws;
    unsigned short* w1t =
        (unsigned short*)((char*)d_ws + (size_t)n_node_elems * 2);

    const int n4 = n_node_elems / 4;
    const int nblk_nodes = (n4 + 255) / 256;
    cvt_kernel<<<nblk_nodes + 8, 256, 0, stream>>>(node_emb, nodes_bf16, n4,
                                                   W1, w1t, nblk_nodes);

    const int nblk = (E + 255) / 256;
    edge_mlp_kernel<<<nblk, 512, 0, stream>>>(nodes_bf16, w1t, eidx,
                                              b1, W2, b2, out, E, n_nodes);
}

// Round 4
// 166.800 us; speedup vs baseline: 1.1465x; 1.1465x over previous
//
#include <hip/hip_runtime.h>

typedef __attribute__((ext_vector_type(8))) short short8;
typedef __attribute__((ext_vector_type(4))) short short4v;
typedef __attribute__((ext_vector_type(4))) float floatx4;

// fp32 -> bf16 round-to-nearest-even (inputs finite)
static __device__ __forceinline__ unsigned short f2bf(float f) {
    union { float f; unsigned int u; } v; v.f = f;
    unsigned int u = v.u;
    return (unsigned short)((u + 0x7FFFu + ((u >> 16) & 1u)) >> 16);
}
static __device__ __forceinline__ float bf2f(short x) {
    return __uint_as_float(((unsigned int)(unsigned short)x) << 16);
}

// W1 [256,128] fp32 -> WT [256,128] bf16, where WT[n'][k]:
//   n' <  128 (Y1 cols): WT[n'][k] = W1[k][n']
//   n' >= 128 (Y2 cols): WT[n'][k] = W1[128+k][n'-128]
// 8 blocks; LDS-tiled so global read and write are both coalesced.
__global__ void cvt_wt_kernel(const float* __restrict__ w1,
                              unsigned short* __restrict__ wt) {
    __shared__ unsigned short sT[32 * 130];
    const int b = blockIdx.x;            // 0..7 -> W1 k-rows [b*32, b*32+32)
    const int kg0 = b * 32;
    const int h = (kg0 >= 128) ? 1 : 0;  // which half of W1
    const int kk0 = kg0 & 127;           // k offset within the half
    const int tid = threadIdx.x;
#pragma unroll
    for (int i = 0; i < 16; i++) {       // load 32x128, coalesced in n
        int idx = tid + i * 256;
        int k = idx >> 7, n = idx & 127;
        sT[k * 130 + n] = f2bf(w1[(kg0 + k) * 128 + n]);
    }
    __syncthreads();
#pragma unroll
    for (int i = 0; i < 16; i++) {       // store, coalesced in k
        int idx = tid + i * 256;
        int n = idx >> 5, k = idx & 31;
        wt[(h * 128 + n) * 128 + kk0 + k] = sT[k * 130 + n];
    }
}

// Phase 1: Y[n][0:128] = x_n @ W1_top + b1 ; Y[n][128:256] = x_n @ W1_bot
// Transposed MFMA (A = WT rows = out-cols, B = X rows = nodes), so the C
// layout (row=outcol, col=node) packs to short4 row-stores directly.
// IN-PLACE: Y (bf16, 512B/row) overwrites X (fp32, 512B/row). Safe: each
// lane reads only its own row, all loads precede all stores in program
// order, waves/blocks own disjoint row ranges. xy must NOT be __restrict__.
__global__ __launch_bounds__(256) void node_gemm_kernel(
    float* xy,                                 // in: X fp32 [N,128]; out: Y bf16 [N,256]
    const unsigned short* __restrict__ wt,     // [256,128] bf16
    const float* __restrict__ b1, int N)
{
    __shared__ unsigned short sW[256 * 128];   // 64KB, slot-swizzled

    const int tid = threadIdx.x;
    const int lane = tid & 63, wave = tid >> 6;
    const int l15 = lane & 15, lq = lane >> 4;

    // Stage WT: 16B slot s of row r stored at slot s^(r&15).
#pragma unroll
    for (int i = 0; i < 16; i++) {
        int u = tid + i * 256;                 // 0..4095 16B-units
        int r = u >> 4, s = u & 15;
        *(short8*)&sW[r * 128 + ((s ^ r) & 15) * 8] =
            *(const short8*)&wt[r * 128 + s * 8];
    }
    __syncthreads();

    const int n0 = blockIdx.x * 64 + wave * 16;
    const int nr = n0 + l15;
    const int nc = (nr < N) ? nr : (N - 1);
    const float* xrow = xy + (size_t)nc * 128;

    floatx4 acc[16];
#pragma unroll
    for (int mt = 0; mt < 16; mt++) acc[mt] = (floatx4){0.f, 0.f, 0.f, 0.f};

#pragma unroll
    for (int ks = 0; ks < 4; ks++) {
        const float4 xa = *(const float4*)(xrow + ks * 32 + lq * 8);
        const float4 xb = *(const float4*)(xrow + ks * 32 + lq * 8 + 4);
        short8 bf;
        bf[0] = (short)f2bf(xa.x); bf[1] = (short)f2bf(xa.y);
        bf[2] = (short)f2bf(xa.z); bf[3] = (short)f2bf(xa.w);
        bf[4] = (short)f2bf(xb.x); bf[5] = (short)f2bf(xb.y);
        bf[6] = (short)f2bf(xb.z); bf[7] = (short)f2bf(xb.w);
#pragma unroll
        for (int mt = 0; mt < 16; mt++) {
            const short8 af = *(const short8*)
                &sW[(mt * 16 + l15) * 128 + (((ks * 4 + lq) ^ l15) & 15) * 8];
            acc[mt] = __builtin_amdgcn_mfma_f32_16x16x32_bf16(af, bf, acc[mt], 0, 0, 0);
        }
    }

    if (nr < N) {
        unsigned short* yrow = (unsigned short*)xy + (size_t)nr * 256;
#pragma unroll
        for (int mt = 0; mt < 16; mt++) {
            const int oc = mt * 16 + lq * 4;   // out-col base (C row = lq*4+i)
            float4 bb = (mt < 8) ? *(const float4*)&b1[oc]
                                 : (float4){0.f, 0.f, 0.f, 0.f};
            short4v pk;
            pk[0] = (short)f2bf(acc[mt][0] + bb.x);
            pk[1] = (short)f2bf(acc[mt][1] + bb.y);
            pk[2] = (short)f2bf(acc[mt][2] + bb.z);
            pk[3] = (short)f2bf(acc[mt][3] + bb.w);
            *(short4v*)(yrow + oc) = pk;       // 8B store
        }
    }
}

// Phase 2: pure gather + reduce. out[e] = relu(Y1[s]+Y2[d]) @ W2 + b2.
// 16 lanes per edge (8 channels each), 4 edge-slots per wave (r=lane>>4),
// 64 edges per wave in 4 chunks; 8 independent 16-line gathers in flight
// per wave; next chunk's indices pipelined under the loads.
__global__ __launch_bounds__(256) void edge_kernel(
    const unsigned short* __restrict__ Y,      // [N,256] bf16 (rows 512B)
    const int* __restrict__ eidx,              // [2,E] int32
    const float* __restrict__ w2,              // [128,2]
    const float* __restrict__ b2,              // [2]
    float* __restrict__ out,                   // [E,2]
    int E, int n_nodes)
{
    const int tid = threadIdx.x;
    const int lane = tid & 63, wave = tid >> 6;
    const int r = lane >> 4, cl = lane & 15;

    // per-lane W2 slice for channels c = cl*8 + j
    float w20[8], w21[8];
#pragma unroll
    for (int q = 0; q < 4; q++) {
        const float4 f = *(const float4*)&w2[cl * 16 + q * 4];
        w20[q * 2]     = f.x; w21[q * 2]     = f.y;
        w20[q * 2 + 1] = f.z; w21[q * 2 + 1] = f.w;
    }
    const float bb0 = b2[0], bb1 = b2[1];

    const long eb = (long)blockIdx.x * 256 + wave * 64;
    const char* Yb = (const char*)Y;

    int sg[4], dg[4];
#pragma unroll
    for (int g = 0; g < 4; g++) {              // indices for chunk 0
        long e = eb + g * 4 + r; if (e >= E) e = E - 1;
        int s = eidx[e], d = eidx[(long)E + e];
        sg[g] = (s < 0) ? 0 : (s >= n_nodes ? n_nodes - 1 : s);
        dg[g] = (d < 0) ? 0 : (d >= n_nodes ? n_nodes - 1 : d);
    }

    for (int ch = 0; ch < 4; ch++) {
        const long e0 = eb + ch * 16;
        short8 v1[4], v2[4];
#pragma unroll
        for (int g = 0; g < 4; g++) {          // 8 gathers in flight
            v1[g] = *(const short8*)(Yb + (size_t)sg[g] * 512 + cl * 16);
            v2[g] = *(const short8*)(Yb + (size_t)dg[g] * 512 + 256 + cl * 16);
        }
        if (ch < 3) {                          // pipeline next chunk's indices
#pragma unroll
            for (int g = 0; g < 4; g++) {
                long e = e0 + 16 + g * 4 + r; if (e >= E) e = E - 1;
                int s = eidx[e], d = eidx[(long)E + e];
                sg[g] = (s < 0) ? 0 : (s >= n_nodes ? n_nodes - 1 : s);
                dg[g] = (d < 0) ? 0 : (d >= n_nodes ? n_nodes - 1 : d);
            }
        }
#pragma unroll
        for (int g = 0; g < 4; g++) {
            float p0 = 0.f, p1 = 0.f;
#pragma unroll
            for (int j = 0; j < 8; j++) {
                float f = bf2f(v1[g][j]) + bf2f(v2[g][j]);  // b1 folded into Y1
                f = fmaxf(f, 0.f);
                p0 = fmaf(f, w20[j], p0);
                p1 = fmaf(f, w21[j], p1);
            }
#pragma unroll
            for (int m = 1; m < 16; m <<= 1) { // reduce over 16 cl-lanes
                p0 += __shfl_xor(p0, m, 64);
                p1 += __shfl_xor(p1, m, 64);
            }
            if (cl == 0) {
                const long e = e0 + g * 4 + r;
                if (e < E) {
                    float2 o; o.x = p0 + bb0; o.y = p1 + bb1;
                    *(float2*)&out[e * 2] = o;
                }
            }
        }
    }
}

extern "C" void kernel_launch(void* const* d_in, const int* in_sizes, int n_in,
                              void* d_out, int out_size, void* d_ws, size_t ws_size,
                              hipStream_t stream) {
    float*       xy   = (float*)d_in[0];       // X fp32 in, Y bf16 out (in-place)
    const int*   eidx = (const int*)d_in[1];
    const float* W1   = (const float*)d_in[2];
    const float* b1   = (const float*)d_in[3];
    const float* W2   = (const float*)d_in[4];
    const float* b2   = (const float*)d_in[5];
    float* out = (float*)d_out;

    const int n_node_elems = in_sizes[0];      // N*128
    const int N = n_node_elems / 128;
    const int E = in_sizes[1] / 2;

    unsigned short* wt = (unsigned short*)d_ws;  // 64KB

    cvt_wt_kernel<<<8, 256, 0, stream>>>(W1, wt);

    const int nblk1 = (N + 63) / 64;
    node_gemm_kernel<<<nblk1, 256, 0, stream>>>(xy, wt, b1, N);

    const int nblk2 = (E + 255) / 256;
    edge_kernel<<<nblk2, 256, 0, stream>>>((const unsigned short*)xy, eidx,
                                           W2, b2, out, E, N);
}

// Round 6
// 164.037 us; speedup vs baseline: 1.1658x; 1.0168x over previous
//
#include <hip/hip_runtime.h>

typedef __attribute__((ext_vector_type(8))) short short8;
typedef __attribute__((ext_vector_type(4))) short short4v;
typedef __attribute__((ext_vector_type(4))) float floatx4;
typedef __attribute__((ext_vector_type(2))) float floatx2;  // native vec: ok for NT builtins

// fp32 -> bf16 round-to-nearest-even (inputs finite)
static __device__ __forceinline__ unsigned short f2bf(float f) {
    union { float f; unsigned int u; } v; v.f = f;
    unsigned int u = v.u;
    return (unsigned short)((u + 0x7FFFu + ((u >> 16) & 1u)) >> 16);
}
static __device__ __forceinline__ float bf2f(short x) {
    return __uint_as_float(((unsigned int)(unsigned short)x) << 16);
}

// W1 [256,128] fp32 -> WT [256,128] bf16:
//   n' <  128: WT[n'][k] = W1[k][n']        (Y1 cols, k = top half)
//   n' >= 128: WT[n'][k] = W1[128+k][n'-128] (Y2 cols, k = bottom half)
__global__ void cvt_wt_kernel(const float* __restrict__ w1,
                              unsigned short* __restrict__ wt) {
    __shared__ unsigned short sT[32 * 130];
    const int b = blockIdx.x;            // 0..7 -> W1 k-rows [b*32, b*32+32)
    const int kg0 = b * 32;
    const int h = (kg0 >= 128) ? 1 : 0;
    const int kk0 = kg0 & 127;
    const int tid = threadIdx.x;
#pragma unroll
    for (int i = 0; i < 16; i++) {       // load 32x128, coalesced in n
        int idx = tid + i * 256;
        int k = idx >> 7, n = idx & 127;
        sT[k * 130 + n] = f2bf(w1[(kg0 + k) * 128 + n]);
    }
    __syncthreads();
#pragma unroll
    for (int i = 0; i < 16; i++) {       // store, coalesced in k
        int idx = tid + i * 256;
        int n = idx >> 5, k = idx & 31;
        wt[(h * 128 + n) * 128 + kk0 + k] = sT[k * 130 + n];
    }
}

// Phase 1: Y[n] = [x_n@W1_top + b1 | x_n@W1_bot], bf16, IN-PLACE over X.
// r4 post-mortem: 256-thr blocks + 64KB LDS = 8 waves/CU (25% occ) made this
// ~2x over its 102MB streaming floor. Now 512 thr / 128 rows per block ->
// 16 waves/CU, and x loads grouped 4x float4 ahead of the MFMA burst.
// In-place safety: each lane reads only its own row; all loads precede all
// stores in program order; blocks own disjoint rows. xy NOT __restrict__.
__global__ __launch_bounds__(512, 4) void node_gemm_kernel(
    float* xy,                                 // in: X fp32 [N,128]; out: Y bf16 [N,256]
    const unsigned short* __restrict__ wt,     // [256,128] bf16 (pre-transposed)
    const float* __restrict__ b1, int N)
{
    __shared__ unsigned short sW[256 * 128];   // 64KB, slot-swizzled

    const int tid = threadIdx.x;
    const int lane = tid & 63, wave = tid >> 6;
    const int l15 = lane & 15, lq = lane >> 4;

    // Stage WT: 16B slot s of row r stored at slot s^(r&15).
#pragma unroll
    for (int i = 0; i < 8; i++) {
        int u = tid + i * 512;                 // 0..4095 16B-units
        int r = u >> 4, s = u & 15;
        *(short8*)&sW[r * 128 + ((s ^ r) & 15) * 8] =
            *(const short8*)&wt[r * 128 + s * 8];
    }
    __syncthreads();

    const int nr = blockIdx.x * 128 + wave * 16 + l15;
    const int nc = (nr < N) ? nr : (N - 1);
    const float* xrow = xy + (size_t)nc * 128;

    floatx4 acc[16];
#pragma unroll
    for (int mt = 0; mt < 16; mt++) acc[mt] = (floatx4){0.f, 0.f, 0.f, 0.f};

#pragma unroll
    for (int kh = 0; kh < 2; kh++) {           // two k-halves of 64
        float4 xf[4];
#pragma unroll
        for (int q = 0; q < 4; q++)            // 4 loads in flight
            xf[q] = *(const float4*)(xrow + kh * 64 + (q >> 1) * 32 + lq * 8
                                     + (q & 1) * 4);
        short8 bf[2];
#pragma unroll
        for (int t = 0; t < 2; t++) {
            bf[t][0] = (short)f2bf(xf[2 * t].x);
            bf[t][1] = (short)f2bf(xf[2 * t].y);
            bf[t][2] = (short)f2bf(xf[2 * t].z);
            bf[t][3] = (short)f2bf(xf[2 * t].w);
            bf[t][4] = (short)f2bf(xf[2 * t + 1].x);
            bf[t][5] = (short)f2bf(xf[2 * t + 1].y);
            bf[t][6] = (short)f2bf(xf[2 * t + 1].z);
            bf[t][7] = (short)f2bf(xf[2 * t + 1].w);
        }
#pragma unroll
        for (int t = 0; t < 2; t++) {
            const int ks = kh * 2 + t;
#pragma unroll
            for (int mt = 0; mt < 16; mt++) {
                const short8 af = *(const short8*)
                    &sW[(mt * 16 + l15) * 128 + (((ks * 4 + lq) ^ l15) & 15) * 8];
                acc[mt] = __builtin_amdgcn_mfma_f32_16x16x32_bf16(af, bf[t],
                                                                  acc[mt], 0, 0, 0);
            }
        }
    }

    if (nr < N) {
        unsigned short* yrow = (unsigned short*)xy + (size_t)nr * 256;
#pragma unroll
        for (int mt = 0; mt < 16; mt++) {
            const int oc = mt * 16 + lq * 4;   // out-col base (C row = lq*4+i)
            float4 bb = (mt < 8) ? *(const float4*)&b1[oc]
                                 : (float4){0.f, 0.f, 0.f, 0.f};
            short4v pk;
            pk[0] = (short)f2bf(acc[mt][0] + bb.x);
            pk[1] = (short)f2bf(acc[mt][1] + bb.y);
            pk[2] = (short)f2bf(acc[mt][2] + bb.z);
            pk[3] = (short)f2bf(acc[mt][3] + bb.w);
            *(short4v*)(yrow + oc) = pk;       // 8B store
        }
    }
}

// Phase 2: pure gather + reduce. out[e] = relu(Y1[s]+Y2[d]) @ W2 + b2.
// 16 lanes per edge, 16-edge chunks DOUBLE-BUFFERED: loads of chunk i+1 stay
// in flight under compute of chunk i (r4 was bursty: 8 loads then a dead
// compute window -> miss-path concurrency underused). NT loads for indices,
// NT stores for out (keep L2 for the Y table).
__global__ __launch_bounds__(256) void edge_kernel(
    const unsigned short* __restrict__ Y,      // [N,256] bf16 (rows 512B)
    const int* __restrict__ eidx,              // [2,E] int32
    const float* __restrict__ w2,              // [128,2]
    const float* __restrict__ b2,              // [2]
    float* __restrict__ out,                   // [E,2]
    int E, int n_nodes)
{
    const int tid = threadIdx.x;
    const int lane = tid & 63, wave = tid >> 6;
    const int r = lane >> 4, cl = lane & 15;

    float w20[8], w21[8];                      // W2 slice for ch c = cl*8 + j
#pragma unroll
    for (int q = 0; q < 4; q++) {
        const float4 f = *(const float4*)&w2[cl * 16 + q * 4];
        w20[q * 2]     = f.x; w21[q * 2]     = f.y;
        w20[q * 2 + 1] = f.z; w21[q * 2 + 1] = f.w;
    }
    const float bb0 = b2[0], bb1 = b2[1];

    const long eb = (long)blockIdx.x * 256 + wave * 64;
    const char* Yb = (const char*)Y;

    int sg[4], dg[4];
    short8 buf[2][2][4];                       // [phase][src/dst][group]

#define LOAD_IDX(CH)                                                        \
    _Pragma("unroll")                                                       \
    for (int g = 0; g < 4; g++) {                                           \
        long e = eb + (CH) * 16 + g * 4 + r; if (e >= E) e = E - 1;         \
        int s = __builtin_nontemporal_load(&eidx[e]);                       \
        int d = __builtin_nontemporal_load(&eidx[(long)E + e]);             \
        sg[g] = (s < 0) ? 0 : (s >= n_nodes ? n_nodes - 1 : s);             \
        dg[g] = (d < 0) ? 0 : (d >= n_nodes ? n_nodes - 1 : d);             \
    }
#define LOAD_Y(P)                                                           \
    _Pragma("unroll")                                                       \
    for (int g = 0; g < 4; g++) {                                           \
        buf[P][0][g] = *(const short8*)(Yb + (size_t)sg[g] * 512 + cl * 16);\
        buf[P][1][g] = *(const short8*)(Yb + (size_t)dg[g] * 512 + 256      \
                                        + cl * 16);                         \
    }

    LOAD_IDX(0); LOAD_Y(0);
    LOAD_IDX(1); LOAD_Y(1);

    for (int ch = 0; ch < 4; ch++) {
        const int p = ch & 1;
        if (ch < 2) { LOAD_IDX(ch + 2); }      // idx for the refill below
#pragma unroll
        for (int g = 0; g < 4; g++) {
            float p0 = 0.f, p1 = 0.f;
#pragma unroll
            for (int j = 0; j < 8; j++) {
                float f = bf2f(buf[p][0][g][j]) + bf2f(buf[p][1][g][j]);
                f = fmaxf(f, 0.f);             // b1 folded into Y1
                p0 = fmaf(f, w20[j], p0);
                p1 = fmaf(f, w21[j], p1);
            }
#pragma unroll
            for (int m = 1; m < 16; m <<= 1) { // reduce over 16 cl-lanes
                p0 += __shfl_xor(p0, m, 64);
                p1 += __shfl_xor(p1, m, 64);
            }
            if (cl == 0) {
                const long e = eb + ch * 16 + g * 4 + r;
                if (e < E) {
                    floatx2 o;
                    o.x = p0 + bb0; o.y = p1 + bb1;
                    __builtin_nontemporal_store(o, (floatx2*)&out[e * 2]);
                }
            }
        }
        if (ch < 2) { LOAD_Y(p); }             // refill freed buffer (chunk ch+2)
    }
#undef LOAD_IDX
#undef LOAD_Y
}

extern "C" void kernel_launch(void* const* d_in, const int* in_sizes, int n_in,
                              void* d_out, int out_size, void* d_ws, size_t ws_size,
                              hipStream_t stream) {
    float*       xy   = (float*)d_in[0];       // X fp32 in, Y bf16 out (in-place)
    const int*   eidx = (const int*)d_in[1];
    const float* W1   = (const float*)d_in[2];
    const float* b1   = (const float*)d_in[3];
    const float* W2   = (const float*)d_in[4];
    const float* b2   = (const float*)d_in[5];
    float* out = (float*)d_out;

    const int n_node_elems = in_sizes[0];      // N*128
    const int N = n_node_elems / 128;
    const int E = in_sizes[1] / 2;

    unsigned short* wt = (unsigned short*)d_ws;  // 64KB

    cvt_wt_kernel<<<8, 256, 0, stream>>>(W1, wt);

    const int nblk1 = (N + 127) / 128;
    node_gemm_kernel<<<nblk1, 512, 0, stream>>>(xy, wt, b1, N);

    const int nblk2 = (E + 255) / 256;
    edge_kernel<<<nblk2, 256, 0, stream>>>((const unsigned short*)xy, eidx,
                                           W2, b2, out, E, N);
}